// Round 7
// baseline (134.317 us; speedup 1.0000x reference)
//
#include <hip/hip_runtime.h>
#include <math.h>

// Problem constants
#define BB 4
#define TT 4096
#define CC 1024
#define HS 64
#define KSEL 2048
#define NSPL 16   // KV splits per row-block
#define SWLOG 8   // split width = 256
#define SW 256

typedef float f32x4 __attribute__((ext_vector_type(4)));
typedef short short8 __attribute__((ext_vector_type(8)));

__device__ __forceinline__ unsigned short f2bf(float f) {
  union { float f; unsigned int u; } c;
  c.f = f;
  const unsigned int u = c.u;
  return (unsigned short)((u + 0x7FFFu + ((u >> 16) & 1u)) >> 16);  // RTNE
}

// packed f32x2 -> bf16x2 (RTNE), single HW instruction
__device__ __forceinline__ unsigned cvtpk(float lo, float hi) {
  unsigned r;
  asm("v_cvt_pk_bf16_f32 %0, %1, %2" : "=v"(r) : "v"(lo), "v"(hi));
  return r;
}

// ---------------------------------------------------------------------------
// conv_w: Wq|Wk|Wv fp32 -> bf16 B-fragment layout. ALSO zeroes the atomic
// accumulators (xsum, L, out) -- replaces a dedicated memset dispatch.
// 128 blocks x 256 thr; conversion uses gid<24576.
// ---------------------------------------------------------------------------
__global__ __launch_bounds__(256) void conv_w(const float* __restrict__ Wq,
                                              const float* __restrict__ Wk,
                                              const float* __restrict__ Wv,
                                              unsigned short* __restrict__ wbf,
                                              float* __restrict__ xsum,
                                              float* __restrict__ L,
                                              float* __restrict__ out) {
  const int gid = blockIdx.x * 256 + threadIdx.x;  // 0..32767
  const float4 z4 = make_float4(0.f, 0.f, 0.f, 0.f);
  // zero out (524288 f = 131072 f4), L (8192 f), xsum (4096 f)
#pragma unroll
  for (int e = 0; e < 4; e++) ((float4*)out)[gid + e * 32768] = z4;
  if (gid < 2048) ((float4*)L)[gid] = z4;
  if (gid < 1024) ((float4*)xsum)[gid] = z4;

  if (gid >= 24576) return;
  const int kt = gid / 768;
  const int rem = gid - kt * 768;
  const int nt = rem >> 6, lane = rem & 63;
  const int col = nt * 16 + (lane & 15);
  const float* W = (col < 64) ? Wq : ((col < 128) ? Wk : Wv);
  const int cl = col & 63;
  const int k0 = kt * 32 + (lane >> 4) * 8;
  unsigned short tmp[8];
#pragma unroll
  for (int i = 0; i < 8; i++) tmp[i] = f2bf(W[(size_t)(k0 + i) * HS + cl]);
  uint4 o;
  o.x = tmp[0] | ((unsigned)tmp[1] << 16);
  o.y = tmp[2] | ((unsigned)tmp[3] << 16);
  o.z = tmp[4] | ((unsigned)tmp[5] << 16);
  o.w = tmp[6] | ((unsigned)tmp[7] << 16);
  *(uint4*)(wbf + (size_t)gid * 8) = o;
}

// ---------------------------------------------------------------------------
// fusedproj: reads x ONCE, register-prefetch pipelined. 1024 blocks x 16
// rows (4 blocks/CU). Per 256-col chunk: stage bf16 into XOR-swizzled LDS,
// atomicAdd fp32 column sums into xsum, MFMA against wbf (L2-hot).
// Writes q (prescaled 2^-5), k row-major bf16, V transposed vt[b][d][t].
// ---------------------------------------------------------------------------
#define PR 16
__global__ __launch_bounds__(256) void fusedproj(
    const float* __restrict__ x, const unsigned short* __restrict__ wbf,
    float* __restrict__ xsum, unsigned short* __restrict__ qbf,
    unsigned short* __restrict__ kbf, unsigned short* __restrict__ vtbf) {
  __shared__ unsigned short Xs[PR][256];  // 8 KB, granule-XOR-swizzled
  __shared__ float xsred[4][256];
  const int rb = blockIdx.x;  // 1024 blocks
  const size_t r0 = (size_t)rb * PR;
  const int tid = threadIdx.x;
  const int wid = tid >> 6, lane = tid & 63;
  const int lhi = lane >> 4, llo = lane & 15;
  const int cl = tid & 63, rg = tid >> 6;
  const int bidx = rb >> 8;

  f32x4 acc[3];
#pragma unroll
  for (int n = 0; n < 3; n++) acc[n] = (f32x4){0.f, 0.f, 0.f, 0.f};

  float4 pf[4];
#pragma unroll
  for (int rr = 0; rr < 4; rr++)
    pf[rr] = *(const float4*)(x + (r0 + rg * 4 + rr) * CC + cl * 4);

  for (int ch = 0; ch < 4; ch++) {
    float ps0 = 0.f, ps1 = 0.f, ps2 = 0.f, ps3 = 0.f;
#pragma unroll
    for (int rr = 0; rr < 4; rr++) {
      const int row = rg * 4 + rr;
      float4 v = pf[rr];
      ps0 += v.x; ps1 += v.y; ps2 += v.z; ps3 += v.w;
      *(uint2*)((char*)&Xs[0][0] + row * 512 +
                ((((cl >> 1) ^ (row & 7))) << 4) + ((cl & 1) << 3)) =
          make_uint2(cvtpk(v.x, v.y), cvtpk(v.z, v.w));
    }
    xsred[rg][cl * 4 + 0] = ps0;
    xsred[rg][cl * 4 + 1] = ps1;
    xsred[rg][cl * 4 + 2] = ps2;
    xsred[rg][cl * 4 + 3] = ps3;
    __syncthreads();
    // issue next-chunk prefetch NOW; latency hides under atomic + MFMA
    if (ch < 3) {
#pragma unroll
      for (int rr = 0; rr < 4; rr++)
        pf[rr] = *(const float4*)(x + (r0 + rg * 4 + rr) * CC +
                                  (ch + 1) * 256 + cl * 4);
    }
    atomicAdd(&xsum[bidx * CC + ch * 256 + tid],
              xsred[0][tid] + xsred[1][tid] + xsred[2][tid] + xsred[3][tid]);
#pragma unroll
    for (int ktl = 0; ktl < 8; ktl++) {
      short8 af = *(const short8*)((const char*)&Xs[0][0] + llo * 512 +
                                   ((((ktl << 2) + lhi) ^ (llo & 7)) << 4));
      const unsigned short* bp =
          wbf + (((size_t)(ch * 8 + ktl) * 12 + wid * 3) * 64 + lane) * 8;
#pragma unroll
      for (int n = 0; n < 3; n++) {
        short8 bf = *(const short8*)(bp + n * 64 * 8);
        acc[n] = __builtin_amdgcn_mfma_f32_16x16x32_bf16(af, bf, acc[n], 0, 0, 0);
      }
    }
    __syncthreads();
  }
  const int rbg = (int)r0 + lhi * 4;
#pragma unroll
  for (int n = 0; n < 3; n++) {
    const int col = (wid * 3 + n) * 16 + llo;
    const int mat = col >> 6, cl2 = col & 63;
    if (mat == 0) {
#pragma unroll
      for (int r = 0; r < 4; r++)
        qbf[(size_t)(rbg + r) * HS + cl2] = f2bf(acc[n][r] * 0.03125f);
    } else if (mat == 1) {
#pragma unroll
      for (int r = 0; r < 4; r++)
        kbf[(size_t)(rbg + r) * HS + cl2] = f2bf(acc[n][r]);
    } else {
      const int bb = rbg >> 12, tloc = rbg & (TT - 1);
      *(uint2*)(vtbf + ((size_t)bb * HS + cl2) * TT + tloc) =
          make_uint2(cvtpk(acc[n][0], acc[n][1]), cvtpk(acc[n][2], acc[n][3]));
    }
  }
}

// ---------------------------------------------------------------------------
// rowsums_x: per-block prologue computes w = Wq (Wk^T xsum); main:
// rs[row] = x[row] . w (fp32 exact for selection). 256 blocks x 512 thr.
// ---------------------------------------------------------------------------
__global__ __launch_bounds__(512) void rowsums_x(
    const float* __restrict__ x, const float* __restrict__ Wq,
    const float* __restrict__ Wk, const float* __restrict__ xsum,
    float* __restrict__ rs) {
  __shared__ float xsl[CC];
  __shared__ float kred[8][HS];
  __shared__ float ksl[HS];
  __shared__ float wl[CC];
  const int g = blockIdx.x;
  const int tid = threadIdx.x;
  const int b = g >> 6;
  *(float2*)(xsl + tid * 2) = *(const float2*)(xsum + b * CC + tid * 2);
  __syncthreads();
  {
    const int g8 = tid >> 6, d = tid & 63;
    const float* wkp = Wk + (size_t)(g8 * 128) * HS + d;
    float s = 0.f;
    for (int c = 0; c < 128; c++) s += xsl[g8 * 128 + c] * wkp[(size_t)c * HS];
    kred[g8][d] = s;
  }
  __syncthreads();
  if (tid < 64) {
    float s = 0.f;
#pragma unroll
    for (int g8 = 0; g8 < 8; g8++) s += kred[g8][tid];
    ksl[tid] = s;
  }
  __syncthreads();
#pragma unroll
  for (int p = 0; p < 2; p++) {
    const int c = tid * 2 + p;
    const float* wqp = Wq + (size_t)c * HS;
    float s = 0.f;
#pragma unroll
    for (int d4 = 0; d4 < 16; d4++) {
      float4 a = *(const float4*)(wqp + d4 * 4);
      float4 kk = *(const float4*)(ksl + d4 * 4);
      s += a.x * kk.x + a.y * kk.y + a.z * kk.z + a.w * kk.w;
    }
    wl[c] = s;
  }
  __syncthreads();
  const size_t row = (size_t)g * 64 + (tid >> 3);
  const int qu = tid & 7;
  const float* xr = x + row * CC + qu * 128;
  const float* wr = wl + qu * 128;
  float s = 0.f;
  for (int e = 0; e < 32; e++) {
    float4 v = *(const float4*)(xr + e * 4);
    float4 w4 = *(const float4*)(wr + e * 4);
    s += v.x * w4.x + v.y * w4.y + v.z * w4.z + v.w * w4.w;
  }
  s += __shfl_xor(s, 1);
  s += __shfl_xor(s, 2);
  s += __shfl_xor(s, 4);
  if (qu == 0) rs[row] = s;
}

// ---------------------------------------------------------------------------
// rankk: flag[t] = t in top-2048 of its row (ties: lower index). 512 blocks.
// ---------------------------------------------------------------------------
__global__ __launch_bounds__(256) void rankk(const float* __restrict__ rs,
                                             int* __restrict__ flag) {
  __shared__ float rl[TT];
  const int g = blockIdx.x;  // B*128
  const int b = g >> 7, chunk = g & 127;
  const int tid = threadIdx.x;
  const float* rsb = rs + (size_t)b * TT;
  for (int e = tid; e < TT / 4; e += 256)
    *(float4*)(rl + e * 4) = *(const float4*)(rsb + e * 4);
  __syncthreads();
  const int cand = tid >> 3, qu = tid & 7;
  const int t = chunk * 32 + cand;
  const float my = rl[t];
  int cnt = 0;
  for (int e = 0; e < 128; e++) {
    const int s = qu * 512 + e * 4;
    float4 v = *(const float4*)(rl + s);
    cnt += (v.x > my) || (v.x == my && (s + 0) < t);
    cnt += (v.y > my) || (v.y == my && (s + 1) < t);
    cnt += (v.z > my) || (v.z == my && (s + 2) < t);
    cnt += (v.w > my) || (v.w == my && (s + 3) < t);
  }
  cnt += __shfl_xor(cnt, 1);
  cnt += __shfl_xor(cnt, 2);
  cnt += __shfl_xor(cnt, 4);
  if (qu == 0) flag[(size_t)b * TT + t] = (cnt < KSEL) ? 1 : 0;
}

// ---------------------------------------------------------------------------
// compact: parallel prefix-scan compaction of flags -> ascending idx.
// ---------------------------------------------------------------------------
__global__ __launch_bounds__(256) void compact(const int* __restrict__ flag,
                                               int* __restrict__ idx) {
  __shared__ int sums[256];
  const int b = blockIdx.x;
  const int tid = threadIdx.x;
  const int* fb = flag + (size_t)b * TT;
  const int base = tid * 16;
  int f[16];
  int cnt = 0;
#pragma unroll
  for (int e = 0; e < 16; e++) { f[e] = fb[base + e]; cnt += f[e]; }
  sums[tid] = cnt;
  __syncthreads();
  for (int d = 1; d < 256; d <<= 1) {
    int v = (tid >= d) ? sums[tid - d] : 0;
    __syncthreads();
    sums[tid] += v;
    __syncthreads();
  }
  int pos = sums[tid] - cnt;
#pragma unroll
  for (int e = 0; e < 16; e++)
    if (f[e]) idx[(size_t)b * KSEL + (pos++)] = base + e;
}

// ---------------------------------------------------------------------------
// attn_mfma: swapped-operand QK^T + no-max softmax; split partials (plain
// sums) accumulate DIRECTLY into out/L via fp32 atomics -- no pacc round
// trip, no combine kernel. grid (rb=64, zz=4, b=4); wave = one KV split.
// ---------------------------------------------------------------------------
struct KF { short8 a0, a1, b0, b1; };
struct VF { short8 v0, v1, v2, v3; };

__global__ __launch_bounds__(256) void attn_mfma(
    const unsigned short* __restrict__ qbf,
    const unsigned short* __restrict__ kbf,
    const unsigned short* __restrict__ vtbf, const int* __restrict__ idx,
    float* __restrict__ L, float* __restrict__ out) {
  __shared__ unsigned short P_lds[4][32][40];
  const int rb = blockIdx.x;
  const int zz = blockIdx.y;
  const int b = blockIdx.z;
  const int tid = threadIdx.x;
  const int wid = tid >> 6, lane = tid & 63;
  const int s = zz * 4 + wid;  // split 0..15
  const size_t rbase = (size_t)b * KSEL + rb * 32;
  const int tmaxblk = idx[rbase + 31];
  const int jlo = s << SWLOG;
  if (jlo > tmaxblk) return;

  const int lhi = lane >> 4, llo = lane & 15;
  const int trow0 = idx[rbase + llo];
  const int trow1 = idx[rbase + 16 + llo];
  short8 qf[2][2];
  {
    const unsigned short* qp0 = qbf + ((size_t)b * TT + trow0) * HS + lhi * 8;
    const unsigned short* qp1 = qbf + ((size_t)b * TT + trow1) * HS + lhi * 8;
    qf[0][0] = *(const short8*)(qp0);
    qf[0][1] = *(const short8*)(qp0 + 32);
    qf[1][0] = *(const short8*)(qp1);
    qf[1][1] = *(const short8*)(qp1 + 32);
  }
  f32x4 o[2][4];
#pragma unroll
  for (int mtt = 0; mtt < 2; mtt++)
#pragma unroll
    for (int n = 0; n < 4; n++) o[mtt][n] = (f32x4){0.f, 0.f, 0.f, 0.f};
  float lsum[2] = {0.f, 0.f};

  const unsigned short* kb = kbf + (size_t)b * TT * HS;
  const unsigned short* vb = vtbf + (size_t)b * HS * TT;
  const int jend = min(tmaxblk + 1, jlo + SW);

  auto loadK = [&](int j0) {
    KF K;
    const unsigned short* kp = kb + (size_t)(j0 + llo) * HS + lhi * 8;
    K.a0 = *(const short8*)(kp);
    K.a1 = *(const short8*)(kp + 32);
    K.b0 = *(const short8*)(kp + 16 * HS);
    K.b1 = *(const short8*)(kp + 16 * HS + 32);
    return K;
  };
  auto loadV = [&](int j0) {
    VF V;
    const unsigned short* vp = vb + (size_t)llo * TT + j0 + lhi * 8;
    V.v0 = *(const short8*)(vp);
    V.v1 = *(const short8*)(vp + 16 * TT);
    V.v2 = *(const short8*)(vp + 32 * TT);
    V.v3 = *(const short8*)(vp + 48 * TT);
    return V;
  };

  auto body = [&](int j0, const KF& K, const VF& V) {
    f32x4 sc[2][2];
#pragma unroll
    for (int mtt = 0; mtt < 2; mtt++) {
      f32x4 a = (f32x4){0.f, 0.f, 0.f, 0.f};
      a = __builtin_amdgcn_mfma_f32_16x16x32_bf16(K.a0, qf[mtt][0], a, 0, 0, 0);
      a = __builtin_amdgcn_mfma_f32_16x16x32_bf16(K.a1, qf[mtt][1], a, 0, 0, 0);
      sc[mtt][0] = a;
      f32x4 c = (f32x4){0.f, 0.f, 0.f, 0.f};
      c = __builtin_amdgcn_mfma_f32_16x16x32_bf16(K.b0, qf[mtt][0], c, 0, 0, 0);
      c = __builtin_amdgcn_mfma_f32_16x16x32_bf16(K.b1, qf[mtt][1], c, 0, 0, 0);
      sc[mtt][1] = c;
    }
#pragma unroll
    for (int mtt = 0; mtt < 2; mtt++) {
      const int tr = (mtt == 0) ? trow0 : trow1;
      float p[8];
#pragma unroll
      for (int kt = 0; kt < 2; kt++)
#pragma unroll
        for (int r = 0; r < 4; r++) {
          const int kk = j0 + kt * 16 + lhi * 4 + r;
          const float e = __expf(sc[mtt][kt][r]);
          p[kt * 4 + r] = (kk <= tr) ? e : 0.f;
        }
      lsum[mtt] += ((p[0] + p[1]) + (p[2] + p[3])) +
                   ((p[4] + p[5]) + (p[6] + p[7]));
      *(uint2*)&P_lds[wid][mtt * 16 + llo][lhi * 4] =
          make_uint2(cvtpk(p[0], p[1]), cvtpk(p[2], p[3]));
      *(uint2*)&P_lds[wid][mtt * 16 + llo][16 + lhi * 4] =
          make_uint2(cvtpk(p[4], p[5]), cvtpk(p[6], p[7]));
    }
    // PV (same-wave DS ordering -> no barrier needed)
    short8 pa0 = *(const short8*)&P_lds[wid][llo][lhi * 8];
    short8 pa1 = *(const short8*)&P_lds[wid][16 + llo][lhi * 8];
    o[0][0] = __builtin_amdgcn_mfma_f32_16x16x32_bf16(pa0, V.v0, o[0][0], 0, 0, 0);
    o[1][0] = __builtin_amdgcn_mfma_f32_16x16x32_bf16(pa1, V.v0, o[1][0], 0, 0, 0);
    o[0][1] = __builtin_amdgcn_mfma_f32_16x16x32_bf16(pa0, V.v1, o[0][1], 0, 0, 0);
    o[1][1] = __builtin_amdgcn_mfma_f32_16x16x32_bf16(pa1, V.v1, o[1][1], 0, 0, 0);
    o[0][2] = __builtin_amdgcn_mfma_f32_16x16x32_bf16(pa0, V.v2, o[0][2], 0, 0, 0);
    o[1][2] = __builtin_amdgcn_mfma_f32_16x16x32_bf16(pa1, V.v2, o[1][2], 0, 0, 0);
    o[0][3] = __builtin_amdgcn_mfma_f32_16x16x32_bf16(pa0, V.v3, o[0][3], 0, 0, 0);
    o[1][3] = __builtin_amdgcn_mfma_f32_16x16x32_bf16(pa1, V.v3, o[1][3], 0, 0, 0);
  };

  int j0 = jlo;
  KF ka = loadK(j0), kb2;
  VF va = loadV(j0), vb2;
  for (;;) {
    if (j0 + 32 < jend) { kb2 = loadK(j0 + 32); vb2 = loadV(j0 + 32); }
    body(j0, ka, va);
    j0 += 32;
    if (j0 >= jend) break;
    if (j0 + 32 < jend) { ka = loadK(j0 + 32); va = loadV(j0 + 32); }
    body(j0, kb2, vb2);
    j0 += 32;
    if (j0 >= jend) break;
  }

  // epilogue: direct atomic accumulation (combine == plain sum)
  lsum[0] += __shfl_xor(lsum[0], 16);
  lsum[0] += __shfl_xor(lsum[0], 32);
  lsum[1] += __shfl_xor(lsum[1], 16);
  lsum[1] += __shfl_xor(lsum[1], 32);
  if (lane < 16) {
    atomicAdd(&L[rbase + llo], lsum[0]);
    atomicAdd(&L[rbase + 16 + llo], lsum[1]);
  }
#pragma unroll
  for (int mtt = 0; mtt < 2; mtt++)
#pragma unroll
    for (int r = 0; r < 4; r++) {
      float* op = out + (rbase + mtt * 16 + lhi * 4 + r) * HS;
#pragma unroll
      for (int n = 0; n < 4; n++) atomicAdd(op + n * 16 + llo, o[mtt][n][r]);
    }
}

// ---------------------------------------------------------------------------
// normalize: out[row] *= 1/L[row], in place. 512 blocks x 256 thr x float4.
// ---------------------------------------------------------------------------
__global__ __launch_bounds__(256) void normalize(const float* __restrict__ L,
                                                 float* __restrict__ out) {
  const int gid = blockIdx.x * 256 + threadIdx.x;  // x4 floats
  const float invl = 1.0f / L[gid >> 4];
  float4 v = ((float4*)out)[gid];
  v.x *= invl; v.y *= invl; v.z *= invl; v.w *= invl;
  ((float4*)out)[gid] = v;
}

// ---------------------------------------------------------------------------
extern "C" void kernel_launch(void* const* d_in, const int* in_sizes, int n_in,
                              void* d_out, int out_size, void* d_ws,
                              size_t ws_size, hipStream_t stream) {
  const float* x = (const float*)d_in[0];
  const float* Wq = (const float*)d_in[1];
  const float* Wk = (const float*)d_in[2];
  const float* Wv = (const float*)d_in[3];
  float* out = (float*)d_out;

  float* wsf = (float*)d_ws;
  float* xsum = wsf;                                   // 4,096 f
  float* rs = xsum + 4096;                             // 16,384 f
  int* flag = (int*)(rs + 16384);                      // 16,384 i
  float* L = (float*)(flag + 16384);                   // 8,192 f
  unsigned short* wbf = (unsigned short*)(L + 8192);   // 196,608 us
  unsigned short* qbf = wbf + 196608;                  // 1,048,576 us
  unsigned short* kbf = qbf + 1048576;                 // 1,048,576 us
  unsigned short* vtbf = kbf + 1048576;                // 1,048,576 us
  int* idxp = (int*)(vtbf + 1048576);                  // 8,192 i

  conv_w<<<128, 256, 0, stream>>>(Wq, Wk, Wv, wbf, xsum, L, out);
  fusedproj<<<1024, 256, 0, stream>>>(x, wbf, xsum, qbf, kbf, vtbf);
  rowsums_x<<<256, 512, 0, stream>>>(x, Wq, Wk, xsum, rs);
  rankk<<<512, 256, 0, stream>>>(rs, flag);
  compact<<<BB, 256, 0, stream>>>(flag, idxp);
  attn_mfma<<<dim3(64, 4, BB), 256, 0, stream>>>(qbf, kbf, vtbf, idxp, L, out);
  normalize<<<512, 256, 0, stream>>>(L, out);
}